// Round 7
// baseline (309.409 us; speedup 1.0000x reference)
//
#include <hip/hip_runtime.h>
#include <math.h>

#define B_ 8
#define N_ 1024
#define C_ 256
#define CN_ 256
#define EPS_ 1e-6f

// ---------------- threefry2x32 (JAX-compatible) ----------------
__device__ __forceinline__ unsigned rotl32(unsigned x, int r){ return (x<<r)|(x>>(32-r)); }

__device__ float tf_noise(unsigned gid){
  unsigned c0 = (gid >= 4096u) ? gid - 4096u : gid;
  unsigned c1 = c0 + 4096u;
  const unsigned k0 = 0u, k1 = 42u;
  const unsigned ks2 = k0 ^ k1 ^ 0x1BD11BDAu;
  unsigned x0 = c0 + k0, x1 = c1 + k1;
  const int R0[4] = {13,15,26,6};
  const int R1[4] = {17,29,16,24};
  #pragma unroll
  for (int i=0;i<4;i++){ x0 += x1; x1 = rotl32(x1,R0[i]); x1 ^= x0; }
  x0 += k1; x1 += ks2 + 1u;
  #pragma unroll
  for (int i=0;i<4;i++){ x0 += x1; x1 = rotl32(x1,R1[i]); x1 ^= x0; }
  x0 += ks2; x1 += k0 + 2u;
  #pragma unroll
  for (int i=0;i<4;i++){ x0 += x1; x1 = rotl32(x1,R0[i]); x1 ^= x0; }
  x0 += k0; x1 += k1 + 3u;
  #pragma unroll
  for (int i=0;i<4;i++){ x0 += x1; x1 = rotl32(x1,R1[i]); x1 ^= x0; }
  x0 += k1; x1 += ks2 + 4u;
  #pragma unroll
  for (int i=0;i<4;i++){ x0 += x1; x1 = rotl32(x1,R0[i]); x1 ^= x0; }
  x0 += ks2; x1 += k0 + 5u;
  unsigned bits = (gid >= 4096u) ? x1 : x0;
  return __uint_as_float(0x3F800000u | (bits >> 9)) - 1.0f;
}

// ---------------- sq of rows ----------------
__global__ __launch_bounds__(256) void k_sq(const float* __restrict__ x, float* __restrict__ sq){
  int row = blockIdx.x * 4 + (threadIdx.x >> 6);
  int l = threadIdx.x & 63;
  const float* p = x + (size_t)row * C_;
  float s = 0.f;
  #pragma unroll
  for (int t=0;t<4;t++){ float v = p[l + 64*t]; s += v*v; }
  #pragma unroll
  for (int m=32;m;m>>=1) s += __shfl_xor(s, m);
  if (l==0) sq[row] = s;
}

// ---------------- transpose [z][1024][256] -> [z][256][1024], 64x64 tiles ----------------
__global__ __launch_bounds__(256) void k_trx(const float* __restrict__ src, float* __restrict__ dst){
  int z = blockIdx.z, rb = blockIdx.y*64, cb = blockIdx.x*64;
  const float* s = src + (size_t)z*N_*C_;
  float* d = dst + (size_t)z*N_*C_;
  __shared__ float t[64][65];
  int tid = threadIdx.x;
  int hr = tid>>4, c4 = (tid&15)*4;
  #pragma unroll
  for (int p=0;p<4;p++){
    int r = p*16 + hr;
    float4 v = *(const float4*)(s + (size_t)(rb+r)*C_ + cb + c4);
    t[r][c4+0]=v.x; t[r][c4+1]=v.y; t[r][c4+2]=v.z; t[r][c4+3]=v.w;
  }
  __syncthreads();
  int r4 = (tid&15)*4;
  #pragma unroll
  for (int p=0;p<4;p++){
    int c = p*16 + hr;
    *(float4*)(d + (size_t)(cb+c)*N_ + rb + r4) =
      make_float4(t[r4+0][c], t[r4+1][c], t[r4+2][c], t[r4+3][c]);
  }
}

// ---------------- transpose 4 weight mats [256][256] -> WT[z][256][256] ----------------
__global__ __launch_bounds__(256) void k_trw(const float* __restrict__ s0, const float* __restrict__ s1,
                                             const float* __restrict__ s2, const float* __restrict__ s3,
                                             float* __restrict__ dst){
  int z = blockIdx.z;
  const float* s = (z==0)?s0:(z==1)?s1:(z==2)?s2:s3;
  float* d = dst + (size_t)z*C_*C_;
  int rb = blockIdx.y*64, cb = blockIdx.x*64;
  __shared__ float t[64][65];
  int tid = threadIdx.x;
  int hr = tid>>4, c4 = (tid&15)*4;
  #pragma unroll
  for (int p=0;p<4;p++){
    int r = p*16 + hr;
    float4 v = *(const float4*)(s + (size_t)(rb+r)*C_ + cb + c4);
    t[r][c4+0]=v.x; t[r][c4+1]=v.y; t[r][c4+2]=v.z; t[r][c4+3]=v.w;
  }
  __syncthreads();
  int r4 = (tid&15)*4;
  #pragma unroll
  for (int p=0;p<4;p++){
    int c = p*16 + hr;
    *(float4*)(d + (size_t)(cb+c)*C_ + rb + r4) =
      make_float4(t[r4+0][c], t[r4+1][c], t[r4+2][c], t[r4+3][c]);
  }
}

// K-major staging: A-tile [32][128], B-tile [32][64], linear LDS, b128 both ways
#define STAGE_A(SRC, LDA)                                                      \
  _Pragma("unroll")                                                            \
  for (int rno=0;rno<4;rno++){                                                 \
    int l = rno*1024 + tid*4; int k = l>>7, n = l&127;                         \
    *(float4*)&As[l] = *(const float4*)((SRC) + (size_t)(k0+k)*(LDA) + n);     \
  }
#define STAGE_B(SRC, LDB)                                                      \
  _Pragma("unroll")                                                            \
  for (int rno=0;rno<2;rno++){                                                 \
    int l = rno*1024 + tid*4; int k = l>>6, j = l&63;                          \
    *(float4*)&Bs[l] = *(const float4*)((SRC) + (size_t)(k0+k)*(LDB) + j);     \
  }
#define INNER84                                                                \
  _Pragma("unroll")                                                            \
  for (int kk=0;kk<32;kk++){                                                   \
    float4 a0 = *(const float4*)&As[kk*128 + ty*4];                            \
    float4 a1 = *(const float4*)&As[kk*128 + 64 + ty*4];                       \
    float4 b0 = *(const float4*)&Bs[kk*64 + tx*4];                             \
    float av[8]={a0.x,a0.y,a0.z,a0.w,a1.x,a1.y,a1.z,a1.w};                     \
    float bv[4]={b0.x,b0.y,b0.z,b0.w};                                         \
    _Pragma("unroll")                                                          \
    for (int r=0;r<8;r++)                                                      \
      _Pragma("unroll")                                                        \
      for (int c=0;c<4;c++) acc[r][c] += av[r]*bv[c];                          \
  }

// ---------------- dist GEMM: 128x64 tiles, K-major staging from xT ----------------
__global__ __launch_bounds__(256) void k_dist5(const float* __restrict__ xT, const float* __restrict__ sq,
                                               float* __restrict__ dist){
  int b = blockIdx.z, bi = blockIdx.y, bj = blockIdx.x;
  const float* At = xT + (size_t)b*C_*N_ + bi*128;
  const float* Bt = xT + (size_t)b*C_*N_ + bj*64;
  __shared__ float As[32*128];
  __shared__ float Bs[32*64];
  int tid = threadIdx.x, tx = tid&15, ty = tid>>4;
  float acc[8][4] = {};
  for (int k0=0;k0<C_;k0+=32){
    STAGE_A(At, N_)
    STAGE_B(Bt, N_)
    __syncthreads();
    INNER84
    __syncthreads();
  }
  float sqj[4];
  #pragma unroll
  for (int c=0;c<4;c++) sqj[c] = sq[b*N_ + bj*64 + tx*4 + c];
  float* dbase = dist + (size_t)b*N_*N_;
  #pragma unroll
  for (int rr=0;rr<2;rr++)
    #pragma unroll
    for (int r=0;r<4;r++){
      int i = bi*128 + rr*64 + ty*4 + r;
      float si = sq[b*N_ + i];
      float o[4];
      #pragma unroll
      for (int c=0;c<4;c++){
        float d2 = si + sqj[c] - 2.f*acc[rr*4+r][c];
        o[c] = sqrtf(fmaxf(d2, 0.f)) * 0.0625f;
      }
      *(float4*)(dbase + (size_t)i*N_ + bj*64 + tx*4) = make_float4(o[0],o[1],o[2],o[3]);
    }
}

// ---------------- projection GEMM: Y = A @ W^T (+bias), A K-major, W^T K-major ----------------
__global__ __launch_bounds__(256) void k_proj5(const float* __restrict__ AT,
    const float* __restrict__ BT0, const float* __restrict__ BT1, const float* __restrict__ BT2,
    const float* __restrict__ bias,
    float* __restrict__ Y0, float* __restrict__ Y1, float* __restrict__ Y2){
  const float* BT = (blockIdx.z==0)?BT0:(blockIdx.z==1)?BT1:BT2;
  float* Y = (blockIdx.z==0)?Y0:(blockIdx.z==1)?Y1:Y2;
  int bi = blockIdx.y, bj = blockIdx.x;
  int bb = bi>>3, n0 = (bi&7)*128;
  const float* At = AT + (size_t)bb*C_*N_ + n0;
  const float* Bt = BT + bj*64;
  __shared__ float As[32*128];
  __shared__ float Bs[32*64];
  int tid = threadIdx.x, tx = tid&15, ty = tid>>4;
  float acc[8][4] = {};
  for (int k0=0;k0<C_;k0+=32){
    STAGE_A(At, N_)
    STAGE_B(Bt, C_)
    __syncthreads();
    INNER84
    __syncthreads();
  }
  float bs[4];
  #pragma unroll
  for (int c=0;c<4;c++) bs[c] = bias ? bias[bj*64 + tx*4 + c] : 0.f;
  #pragma unroll
  for (int rr=0;rr<2;rr++)
    #pragma unroll
    for (int r=0;r<4;r++){
      int m = bi*128 + rr*64 + ty*4 + r;
      *(float4*)(Y + (size_t)m*C_ + bj*64 + tx*4) =
        make_float4(acc[rr*4+r][0]+bs[0], acc[rr*4+r][1]+bs[1],
                    acc[rr*4+r][2]+bs[2], acc[rr*4+r][3]+bs[3]);
    }
}

// ---------------- per-row 5 smallest -> density (+noise), row max ----------------
__global__ __launch_bounds__(256) void k_top5(const float* __restrict__ dist, float* __restrict__ density,
                                              float* __restrict__ rowmax){
  int row = blockIdx.x * 4 + (threadIdx.x >> 6);
  int l = threadIdx.x & 63;
  const float* p = dist + (size_t)row * N_;
  float t[5] = {1e30f,1e30f,1e30f,1e30f,1e30f};
  float mx = 0.f;
  #pragma unroll
  for (int q2=0;q2<16;q2++){
    float v = p[l + 64*q2];
    mx = fmaxf(mx, v);
    if (v < t[4]){
      t[4] = v;
      #pragma unroll
      for (int a=4;a>0;a--) if (t[a] < t[a-1]) { float tmp=t[a]; t[a]=t[a-1]; t[a-1]=tmp; }
    }
  }
  #pragma unroll
  for (int m=32;m;m>>=1) mx = fmaxf(mx, __shfl_xor(mx, m));
  float sumsq = 0.f;
  int hi = 0;
  #pragma unroll
  for (int a=0;a<5;a++){
    float head = (hi==0)?t[0]:(hi==1)?t[1]:(hi==2)?t[2]:(hi==3)?t[3]:(hi==4)?t[4]:1e30f;
    float m = head;
    #pragma unroll
    for (int mm=32;mm;mm>>=1) m = fminf(m, __shfl_xor(m, mm));
    sumsq += m*m;
    unsigned long long ball = __ballot(head == m);
    if (l == (__ffsll(ball) - 1)) hi++;
  }
  if (l == 0){
    float msq = sumsq / 5.0f;
    density[row] = expf(-msq) + tf_noise((unsigned)row) * 1e-6f;
    rowmax[row] = mx;
  }
}

__global__ __launch_bounds__(256) void k_bmax(const float* __restrict__ rowmax, float* __restrict__ bmax){
  int b = blockIdx.x; int t = threadIdx.x;
  float m = fmaxf(fmaxf(rowmax[b*N_+t], rowmax[b*N_+t+256]),
                  fmaxf(rowmax[b*N_+t+512], rowmax[b*N_+t+768]));
  __shared__ float s[256];
  s[t]=m; __syncthreads();
  for (int d=128; d; d>>=1){ if (t<d) s[t]=fmaxf(s[t],s[t+d]); __syncthreads(); }
  if (t==0) bmax[b]=s[0];
}

// ---------------- d_ind = min dist over higher-density peers; score ----------------
__global__ __launch_bounds__(256) void k_dind(const float* __restrict__ dist, const float* __restrict__ density,
                                              const float* __restrict__ bmax, float* __restrict__ score){
  int row = blockIdx.x * 4 + (threadIdx.x >> 6);
  int b = row >> 10;
  int l = threadIdx.x & 63;
  const float* p = dist + (size_t)row * N_;
  const float* db = density + b*N_;
  float di = density[row];
  float m = bmax[b];
  #pragma unroll
  for (int q2=0;q2<16;q2++){
    int j = l + 64*q2;
    float dj = db[j];
    if (dj > di) m = fminf(m, p[j]);
  }
  #pragma unroll
  for (int mm=32;mm;mm>>=1) m = fminf(m, __shfl_xor(m, mm));
  if (l==0) score[row] = m * di;
}

// ---------------- stable top-256: bitonic with shuffle strides (j<=32) ----------------
__global__ __launch_bounds__(1024) void k_top256(const float* __restrict__ score, int* __restrict__ idxdown){
  int b = blockIdx.x; int t = threadIdx.x;
  __shared__ float sv[1024];
  __shared__ int si[1024];
  float v = score[b*N_ + t];
  int i = t;
  for (int k = 2; k <= 1024; k <<= 1){
    for (int j = k >> 1; j > 0; j >>= 1){
      float v2; int i2;
      if (j >= 64){
        sv[t] = v; si[t] = i;
        __syncthreads();
        v2 = sv[t ^ j]; i2 = si[t ^ j];
        __syncthreads();
      } else {
        v2 = __shfl_xor(v, j);
        i2 = __shfl_xor(i, j);
      }
      bool islo = (t & j) == 0;
      float lov = islo ? v : v2,  hiv = islo ? v2 : v;
      int   loi = islo ? i : i2,  hii = islo ? i2 : i;
      bool prec = (lov > hiv) || (lov == hiv && loi < hii);
      bool up = ((t & k) == 0);
      bool dosw = up ? !prec : prec;
      if (dosw){ v = v2; i = i2; }
    }
  }
  if (t < CN_) idxdown[b*CN_ + t] = i;
}

// ---------------- assign: 4 center-chunks x 64 tokens, first-occurrence argmin ----------------
__global__ __launch_bounds__(256) void k_assign(const float* __restrict__ dist, const int* __restrict__ idxdown,
                                                int* __restrict__ idxclu){
  int b = blockIdx.y;
  int l = threadIdx.x & 63;
  int ch = threadIdx.x >> 6;
  int j = blockIdx.x*64 + l;
  __shared__ int cen[256];
  __shared__ float sd[4][64];
  __shared__ int sk[4][64];
  cen[threadIdx.x] = idxdown[b*CN_ + threadIdx.x];
  __syncthreads();
  const float* dbase = dist + (size_t)b*N_*N_;
  float best = 1e30f; int bk = 0;
  #pragma unroll 8
  for (int kk=0; kk<64; kk++){
    int k = ch*64 + kk;
    float d = dbase[(size_t)cen[k]*N_ + j];
    if (d < best){ best = d; bk = k; }
  }
  sd[ch][l] = best; sk[ch][l] = bk;
  __syncthreads();
  if (ch == 0){
    #pragma unroll
    for (int c2=1;c2<4;c2++){
      float d = sd[c2][l];
      if (d < best){ best = d; bk = sk[c2][l]; }
    }
    idxclu[b*N_ + j] = bk;
  }
}

// ---------------- setcenters + hist + scan + scatter, one kernel per batch ----------------
__global__ __launch_bounds__(256) void k_build2(const int* __restrict__ idxdown, int* __restrict__ idxclu,
                                                int* __restrict__ off, int* __restrict__ cnt,
                                                int* __restrict__ members){
  int b = blockIdx.x; int t = threadIdx.x;
  idxclu[b*N_ + idxdown[b*CN_ + t]] = t;       // setcenters
  __syncthreads();
  __shared__ int sc[256], so[256];
  sc[t] = 0;
  __syncthreads();
  int cl[4];
  #pragma unroll
  for (int i=0;i<4;i++){
    cl[i] = idxclu[b*N_ + i*256 + t];
    atomicAdd(&sc[cl[i]], 1);
  }
  __syncthreads();
  int mine = sc[t];
  so[t] = mine;
  __syncthreads();
  for (int d=1; d<256; d<<=1){
    int v2 = 0;
    if (t>=d) v2 = so[t-d];
    __syncthreads();
    if (t>=d) so[t] += v2;
    __syncthreads();
  }
  int excl = so[t] - mine;
  off[b*CN_+t] = excl;
  cnt[b*CN_+t] = mine;
  sc[t] = excl;
  __syncthreads();
  #pragma unroll
  for (int i=0;i<4;i++){
    int p = atomicAdd(&sc[cl[i]], 1);
    members[b*N_ + p] = i*256 + t;
  }
}

// ---------------- vsum: two-phase parallel ----------------
__global__ __launch_bounds__(256) void k_vsum1(const float* __restrict__ v, float* __restrict__ vsp){
  int p = blockIdx.x;
  int b = p >> 4, s = p & 15;
  int c = threadIdx.x;
  float acc = 0.f;
  const float* base = v + ((size_t)b*N_ + s*64)*C_ + c;
  #pragma unroll 8
  for (int i=0;i<64;i++) acc += base[(size_t)i*C_];
  vsp[(size_t)p*C_ + c] = acc;
}

__global__ __launch_bounds__(256) void k_vsum2(const float* __restrict__ vsp, float* __restrict__ vsum){
  int b = blockIdx.x; int c = threadIdx.x;
  float s = 0.f;
  #pragma unroll
  for (int i=0;i<16;i++) s += vsp[((size_t)b*16 + i)*C_ + c];
  vsum[b*C_ + c] = s;
}

// ---------------- cluster-sparse attention ----------------
__global__ __launch_bounds__(256) void k_attn(const float* __restrict__ q, const float* __restrict__ kmat,
                                              const float* __restrict__ v, const float* __restrict__ vsum,
                                              const int* __restrict__ idxclu, const int* __restrict__ off,
                                              const int* __restrict__ cnt, const int* __restrict__ members,
                                              float* __restrict__ att){
  int bi = blockIdx.x;
  int b = bi >> 10;
  int h = threadIdx.x >> 6, l = threadIdx.x & 63;
  int c = idxclu[bi];
  int o = off[b*CN_ + c], m = cnt[b*CN_ + c];
  int ch = h*64 + l;
  float qv = q[(size_t)bi*C_ + ch];
  float acc = 0.f, den = 0.f;
  const int* mem = members + b*N_ + o;
  for (int t=0;t<m;t++){
    int j = mem[t];
    size_t base = ((size_t)(b*N_ + j))*C_ + ch;
    float p = qv * kmat[base];
    #pragma unroll
    for (int mm=32;mm;mm>>=1) p += __shfl_xor(p, mm);
    float s = p * 0.125f;
    float e = (s == 0.0f) ? 0.0f : expf(s);
    den += e;
    acc += e * v[base];
  }
  float outv = (acc + (EPS_/1024.0f) * vsum[b*C_ + ch]) / (den + EPS_);
  att[(size_t)bi*C_ + ch] = outv;
}

extern "C" void kernel_launch(void* const* d_in, const int* in_sizes, int n_in,
                              void* d_out, int out_size, void* d_ws, size_t ws_size,
                              hipStream_t stream){
  const float* x  = (const float*)d_in[0];
  const float* Wq = (const float*)d_in[1];
  const float* Wk = (const float*)d_in[2];
  const float* Wv = (const float*)d_in[3];
  const float* Wp = (const float*)d_in[4];
  const float* bp = (const float*)d_in[5];
  float* out = (float*)d_out;

  float* ws = (float*)d_ws;
  float* dist    = ws;                                   // 8M floats; later reused as attT
  float* q       = dist + (size_t)B_*N_*N_;              // 2M
  float* kk      = q    + (size_t)B_*N_*C_;
  float* v       = kk   + (size_t)B_*N_*C_;
  float* att     = v    + (size_t)B_*N_*C_;              // 2M; first used as xT
  float* WT      = att  + (size_t)B_*N_*C_;              // 4*65536
  float* vsp     = WT + 4*C_*C_;                         // 128*256
  float* vsum    = vsp + 128*C_;
  float* sq      = vsum + B_*C_;
  float* rowmax  = sq + B_*N_;
  float* bmax    = rowmax + B_*N_;
  float* density = bmax + 16;
  float* score   = density + B_*N_;
  int* idxdown   = (int*)(score + B_*N_);
  int* idxclu    = idxdown + B_*CN_;
  int* cnt       = idxclu + B_*N_;
  int* off       = cnt + B_*CN_;
  int* members   = off + B_*CN_;

  float* xT   = att;    // alias: xT dead before k_attn writes att
  float* attT = dist;   // alias: dist dead after k_assign

  k_trx<<<dim3(4,16,8),256,0,stream>>>(x, xT);
  k_trw<<<dim3(4,4,4),256,0,stream>>>(Wq, Wk, Wv, Wp, WT);
  k_sq<<<B_*N_/4,256,0,stream>>>(x, sq);
  k_dist5<<<dim3(16,8,8),256,0,stream>>>(xT, sq, dist);
  k_top5<<<B_*N_/4,256,0,stream>>>(dist, density, rowmax);
  k_bmax<<<8,256,0,stream>>>(rowmax, bmax);
  k_dind<<<B_*N_/4,256,0,stream>>>(dist, density, bmax, score);
  k_top256<<<8,1024,0,stream>>>(score, idxdown);
  k_assign<<<dim3(16,8),256,0,stream>>>(dist, idxdown, idxclu);
  k_build2<<<8,256,0,stream>>>(idxdown, idxclu, off, cnt, members);
  k_proj5<<<dim3(4,64,3),256,0,stream>>>(xT, WT, WT + C_*C_, WT + 2*C_*C_, nullptr, q, kk, v);
  k_vsum1<<<128,256,0,stream>>>(v, vsp);
  k_vsum2<<<8,256,0,stream>>>(vsp, vsum);
  k_attn<<<B_*N_,256,0,stream>>>(q, kk, v, vsum, idxclu, off, cnt, members, att);
  k_trx<<<dim3(4,16,8),256,0,stream>>>(att, attT);
  k_proj5<<<dim3(4,64,1),256,0,stream>>>(attT, WT + 3*C_*C_, WT + 3*C_*C_, WT + 3*C_*C_, bp, out, out, out);
}